// Round 1
// baseline (75.084 us; speedup 1.0000x reference)
//
#include <hip/hip_runtime.h>

#define BSZ 512
#define NN  500
#define KK  100
#define SS  96
#define HIDN 32

// ---------------- kernel 1: exclusive prefix sum of idx_of_node ----------------
__global__ __launch_bounds__(BSZ) void offs_kernel(const int* __restrict__ idx_of_node,
                                                   int* __restrict__ offs) {
    __shared__ int buf[BSZ];
    int t = threadIdx.x;
    int v = idx_of_node[t];
    buf[t] = v;
    __syncthreads();
    int acc = v;
    for (int d = 1; d < BSZ; d <<= 1) {
        int add = (t >= d) ? buf[t - d] : 0;
        __syncthreads();
        acc += add;
        buf[t] = acc;
        __syncthreads();
    }
    offs[t] = acc - v;  // exclusive prefix
}

// ---------------- kernel 2: out = x (float4 grid-stride copy) ----------------
__global__ __launch_bounds__(256) void copy_kernel(const float4* __restrict__ src,
                                                   float4* __restrict__ dst, int n4) {
    int i = blockIdx.x * 256 + threadIdx.x;
    int stride = gridDim.x * 256;
    for (; i < n4; i += stride) dst[i] = src[i];
}

// ---------------- kernel 3: gather -> MLP -> gate -> masked scatter ----------------
__global__ __launch_bounds__(256) void scatter_kernel(
    const float* __restrict__ y, const float* __restrict__ W1,
    const float* __restrict__ b1, const float* __restrict__ W2,
    const float* __restrict__ b2, const float* __restrict__ mask,
    const float* __restrict__ gumbel, const int* __restrict__ krig_idx,
    const int* __restrict__ offs, float* __restrict__ out) {
    __shared__ float4 w1s[SS * HIDN / 4];  // 12 KB, row-major [s][j]
    __shared__ float b1s[HIDN];
    __shared__ float w2s[HIDN * 2];
    __shared__ float b2s[2];
    for (int i = threadIdx.x; i < SS * HIDN / 4; i += 256)
        w1s[i] = reinterpret_cast<const float4*>(W1)[i];
    if (threadIdx.x < HIDN) b1s[threadIdx.x] = b1[threadIdx.x];
    if (threadIdx.x < 2 * HIDN) w2s[threadIdx.x] = W2[threadIdx.x];
    if (threadIdx.x < 2) b2s[threadIdx.x] = b2[threadIdx.x];
    __syncthreads();

    int r = blockIdx.x * 256 + threadIdx.x;
    if (r >= BSZ * KK) return;
    int b = r / KK;
    int node = krig_idx[r];
    const float4* yrow = reinterpret_cast<const float4*>(y + (size_t)(b * NN + node) * SS);

    // pass 1: h = smp @ W1 + b1   (h statically indexed; s4 loop not unrolled)
    float h[HIDN];
#pragma unroll
    for (int j = 0; j < HIDN; ++j) h[j] = b1s[j];
    for (int s4 = 0; s4 < SS / 4; ++s4) {
        float4 v = yrow[s4];
        const float4* wbase = &w1s[s4 * 4 * (HIDN / 4)];
        float vv[4] = {v.x, v.y, v.z, v.w};
#pragma unroll
        for (int q = 0; q < 4; ++q) {
#pragma unroll
            for (int j4 = 0; j4 < HIDN / 4; ++j4) {
                float4 w = wbase[q * (HIDN / 4) + j4];
                h[j4 * 4 + 0] += vv[q] * w.x;
                h[j4 * 4 + 1] += vv[q] * w.y;
                h[j4 * 4 + 2] += vv[q] * w.z;
                h[j4 * 4 + 3] += vv[q] * w.w;
            }
        }
    }
    // logits + gumbel; gate = exact {0,1}
    float l0 = b2s[0], l1 = b2s[1];
#pragma unroll
    for (int j = 0; j < HIDN; ++j) {
        float hr = fmaxf(h[j], 0.0f);
        l0 += hr * w2s[j * 2 + 0];
        l1 += hr * w2s[j * 2 + 1];
    }
    float g0 = gumbel[r * 2 + 0], g1 = gumbel[r * 2 + 1];
    float gb1 = (l1 + g1 > l0 + g0) ? 1.0f : 0.0f;

    // pass 2: out[dst] = gb1 * mask * smp (y-row re-read: L2 hit)
    const float4* mrow = reinterpret_cast<const float4*>(mask + (size_t)r * SS);
    float4* orow = reinterpret_cast<float4*>(out + (size_t)(offs[b] + node) * SS);
    for (int s4 = 0; s4 < SS / 4; ++s4) {
        float4 v = yrow[s4];
        float4 m = mrow[s4];
        float4 o;
        o.x = gb1 * m.x * v.x;
        o.y = gb1 * m.y * v.y;
        o.z = gb1 * m.z * v.z;
        o.w = gb1 * m.w * v.w;
        orow[s4] = o;
    }
}

extern "C" void kernel_launch(void* const* d_in, const int* in_sizes, int n_in,
                              void* d_out, int out_size, void* d_ws, size_t ws_size,
                              hipStream_t stream) {
    const float* x      = (const float*)d_in[0];
    const float* y      = (const float*)d_in[1];
    const float* W1     = (const float*)d_in[2];
    const float* b1     = (const float*)d_in[3];
    const float* W2     = (const float*)d_in[4];
    const float* b2     = (const float*)d_in[5];
    const float* mask   = (const float*)d_in[6];
    const float* gumbel = (const float*)d_in[7];
    const int* krig_idx = (const int*)d_in[8];
    const int* idx_of_node = (const int*)d_in[9];
    float* out = (float*)d_out;
    int* offs = (int*)d_ws;

    offs_kernel<<<1, BSZ, 0, stream>>>(idx_of_node, offs);

    int n4 = BSZ * NN * SS / 4;
    copy_kernel<<<2048, 256, 0, stream>>>(reinterpret_cast<const float4*>(x),
                                          reinterpret_cast<float4*>(out), n4);

    int rows = BSZ * KK;
    scatter_kernel<<<(rows + 255) / 256, 256, 0, stream>>>(
        y, W1, b1, W2, b2, mask, gumbel, krig_idx, offs, out);
}